// Round 3
// baseline (1575.027 us; speedup 1.0000x reference)
//
#include <hip/hip_runtime.h>

typedef unsigned short ushort_t;
typedef unsigned int uint_t;

#define B_SZ 2048
#define C_SZ 100
#define P_SZ 128
#define D_SZ 192

__device__ __forceinline__ float b2f(ushort_t u) {
    union { uint_t i; float f; } v; v.i = ((uint_t)u) << 16; return v.f;
}
__device__ __forceinline__ ushort_t f2b(float f) {
    uint_t x = __float_as_uint(f);
    uint_t r = x + 0x7fffu + ((x >> 16) & 1u);  // round-to-nearest-even
    return (ushort_t)(r >> 16);
}

// ---------------- K0: batch-independent precompute (tiny, fp32 I/O) ----------------
// blocks 0..99   : colT[d*100 + c] = LN(emb_column[c,:])*ln_col_w + ln_col_b
// blocks 100..227: cp[p*192 + d]   = LN(emb_prompt[p,:]) @ W_imp[0:192,:] + b_imp + emb_prompt[p,:]
__global__ __launch_bounds__(192) void precompute(
    const float* __restrict__ emb_column, const float* __restrict__ emb_prompt,
    const float* __restrict__ ln_col_w, const float* __restrict__ ln_col_b,
    const float* __restrict__ ln_prompt_w, const float* __restrict__ ln_prompt_b,
    const float* __restrict__ W_imp, const float* __restrict__ b_imp,
    float* __restrict__ colT, float* __restrict__ cp)
{
    const int r = blockIdx.x;
    const int t = threadIdx.x;            // 0..191  (= d)
    const int wid = t >> 6, lane = t & 63;
    __shared__ float redS[3], redQ[3];
    __shared__ float rowv[192];

    if (r < C_SZ) {
        float v = emb_column[r * D_SZ + t];
        float s = v, q = v * v;
        #pragma unroll
        for (int o = 1; o < 64; o <<= 1) { s += __shfl_xor(s, o); q += __shfl_xor(q, o); }
        if (lane == 0) { redS[wid] = s; redQ[wid] = q; }
        __syncthreads();
        s = redS[0] + redS[1] + redS[2];
        q = redQ[0] + redQ[1] + redQ[2];
        float m = s * (1.f / D_SZ);
        float var = fmaxf(q * (1.f / D_SZ) - m * m, 0.f);
        float rs = rsqrtf(var + 1e-5f);
        float o = (v - m) * rs * ln_col_w[t] + ln_col_b[t];
        colT[t * C_SZ + r] = o;           // transposed store
    } else {
        const int p = r - C_SZ;
        float v = emb_prompt[p * D_SZ + t];
        float s = v, q = v * v;
        #pragma unroll
        for (int o = 1; o < 64; o <<= 1) { s += __shfl_xor(s, o); q += __shfl_xor(q, o); }
        if (lane == 0) { redS[wid] = s; redQ[wid] = q; }
        __syncthreads();
        s = redS[0] + redS[1] + redS[2];
        q = redQ[0] + redQ[1] + redQ[2];
        float m = s * (1.f / D_SZ);
        float var = fmaxf(q * (1.f / D_SZ) - m * m, 0.f);
        float rs = rsqrtf(var + 1e-5f);
        float ln = (v - m) * rs * ln_prompt_w[t] + ln_prompt_b[t];
        rowv[t] = ln;
        __syncthreads();
        float a = b_imp[t] + v;           // + emb_prompt[p][t] (residual)
        for (int e = 0; e < D_SZ; ++e)
            a = fmaf(rowv[e], W_imp[e * D_SZ + t], a);
        cp[p * D_SZ + t] = a;
    }
}

// ---------------- K1: per-batch fully fused (fp32 I/O) ----------------
__global__ __launch_bounds__(256) void fused(
    const float* __restrict__ x, const float* __restrict__ wfe,
    const float* __restrict__ bfe, const float* __restrict__ lnw,
    const float* __restrict__ lnb,
    const float* __restrict__ prev, const float* __restrict__ W_imp,
    const float* __restrict__ wexp, const float* __restrict__ bexp,
    const float* __restrict__ colT, const float* __restrict__ cp,
    float* __restrict__ out)
{
    const int b = blockIdx.x;
    const int tid = threadIdx.x;
    const int w = tid >> 6, lane = tid & 63;

    __shared__ __align__(16) ushort_t xe[C_SZ * D_SZ];   // 38400 B, bf16 x_emb[b]
    __shared__ float ybuf[4][4][D_SZ];                   // 12288 B, y rows -> reused for mask
    __shared__ float prevb[4][4][D_SZ];                  // 12288 B

    // ---- stage 0: x_emb[b] = LN(relu(x*w+b)) -> LDS (bf16) ----
    {
        const float lw0 = lnw[lane],       lb0 = lnb[lane];
        const float lw1 = lnw[lane + 64],  lb1 = lnb[lane + 64];
        const float lw2 = lnw[lane + 128], lb2 = lnb[lane + 128];
        for (int i = 0; i < 25; ++i) {
            const int c = w * 25 + i;
            const float xv = x[b * C_SZ + c];
            const float* wr = wfe + c * D_SZ;
            const float* br = bfe + c * D_SZ;
            float v0 = fmaxf(fmaf(xv, wr[lane],       br[lane]),       0.f);
            float v1 = fmaxf(fmaf(xv, wr[lane + 64],  br[lane + 64]),  0.f);
            float v2 = fmaxf(fmaf(xv, wr[lane + 128], br[lane + 128]), 0.f);
            float s = v0 + v1 + v2;
            float q = v0 * v0 + v1 * v1 + v2 * v2;
            #pragma unroll
            for (int o = 1; o < 64; o <<= 1) { s += __shfl_xor(s, o); q += __shfl_xor(q, o); }
            float m = s * (1.f / D_SZ);
            float var = fmaxf(q * (1.f / D_SZ) - m * m, 0.f);
            float rs = rsqrtf(var + 1e-5f);
            xe[c * D_SZ + lane]       = f2b((v0 - m) * rs * lw0 + lb0);
            xe[c * D_SZ + lane + 64]  = f2b((v1 - m) * rs * lw1 + lb1);
            xe[c * D_SZ + lane + 128] = f2b((v2 - m) * rs * lw2 + lb2);
        }
    }
    __syncthreads();

    const float* W2 = W_imp + D_SZ * D_SZ;   // bottom half of W_imp (rows D..2D-1)

    for (int g = 0; g < 8; ++g) {
        const int pbase = (w * 8 + g) * 4;

        // load 4 prev rows into per-wave LDS
        #pragma unroll
        for (int k = 0; k < 4; ++k) {
            const float* pr = prev + ((size_t)b * P_SZ + pbase + k) * D_SZ;
            prevb[w][k][lane]       = pr[lane];
            prevb[w][k][lane + 64]  = pr[lane + 64];
            prevb[w][k][lane + 128] = pr[lane + 128];
        }

        // prompt GEMM: acc[k][j] = prev[b,p_k,:] @ W2[:, lane+64j]
        float acc[4][3];
        #pragma unroll
        for (int k = 0; k < 4; ++k) { acc[k][0] = acc[k][1] = acc[k][2] = 0.f; }
        for (int e = 0; e < D_SZ; ++e) {
            const float* wrow = W2 + e * D_SZ;
            float w0 = wrow[lane];
            float w1 = wrow[lane + 64];
            float w2 = wrow[lane + 128];
            #pragma unroll
            for (int k = 0; k < 4; ++k) {
                float pe = prevb[w][k][e];
                acc[k][0] = fmaf(pe, w0, acc[k][0]);
                acc[k][1] = fmaf(pe, w1, acc[k][1]);
                acc[k][2] = fmaf(pe, w2, acc[k][2]);
            }
        }
        // y = acc + const_prompt  -> ybuf
        #pragma unroll
        for (int k = 0; k < 4; ++k) {
            const float* cpr = cp + (pbase + k) * D_SZ;
            ybuf[w][k][lane]       = acc[k][0] + cpr[lane];
            ybuf[w][k][lane + 64]  = acc[k][1] + cpr[lane + 64];
            ybuf[w][k][lane + 128] = acc[k][2] + cpr[lane + 128];
        }

        // scores: lane owns c0=lane, c1=lane+64 (if <100)
        float s0[4] = {0.f, 0.f, 0.f, 0.f};
        float s1[4] = {0.f, 0.f, 0.f, 0.f};
        const bool has_c1 = (lane < C_SZ - 64);
        for (int d = 0; d < D_SZ; ++d) {
            float cva = colT[d * C_SZ + lane];
            float cvb = has_c1 ? colT[d * C_SZ + 64 + lane] : 0.f;
            #pragma unroll
            for (int k = 0; k < 4; ++k) {
                float yv = ybuf[w][k][d];
                s0[k] = fmaf(yv, cva, s0[k]);
                s1[k] = fmaf(yv, cvb, s1[k]);
            }
        }
        // softmax over c per k; mask -> ybuf[w][k][0..99]
        #pragma unroll
        for (int k = 0; k < 4; ++k) {
            float mx = s0[k];
            if (has_c1) mx = fmaxf(mx, s1[k]);
            #pragma unroll
            for (int o = 1; o < 64; o <<= 1) mx = fmaxf(mx, __shfl_xor(mx, o));
            float e0 = __expf(s0[k] - mx);
            float e1 = has_c1 ? __expf(s1[k] - mx) : 0.f;
            float ts = e0 + e1;
            #pragma unroll
            for (int o = 1; o < 64; o <<= 1) ts += __shfl_xor(ts, o);
            float inv = 1.f / ts;
            ybuf[w][k][lane] = e0 * inv;
            if (has_c1) ybuf[w][k][64 + lane] = e1 * inv;
        }

        // agg + epilogue
        #pragma unroll
        for (int k = 0; k < 4; ++k) {
            float a0 = 0.f, a1 = 0.f, a2 = 0.f;
            for (int c = 0; c < C_SZ; ++c) {
                float mk = ybuf[w][k][c];
                a0 = fmaf(mk, b2f(xe[c * D_SZ + lane]),       a0);
                a1 = fmaf(mk, b2f(xe[c * D_SZ + 64 + lane]),  a1);
                a2 = fmaf(mk, b2f(xe[c * D_SZ + 128 + lane]), a2);
            }
            const int p = pbase + k;
            float sc = 1.f + wexp[p];
            float bi = bexp[p];
            float* orow = out + ((size_t)b * P_SZ + p) * D_SZ;
            orow[lane]       = fmaf(a0, sc, bi);
            orow[lane + 64]  = fmaf(a1, sc, bi);
            orow[lane + 128] = fmaf(a2, sc, bi);
        }
    }
}

extern "C" void kernel_launch(void* const* d_in, const int* in_sizes, int n_in,
                              void* d_out, int out_size, void* d_ws, size_t ws_size,
                              hipStream_t stream) {
    const float* x           = (const float*)d_in[0];
    const float* prev        = (const float*)d_in[1];
    const float* wfe         = (const float*)d_in[2];
    const float* bfe         = (const float*)d_in[3];
    const float* ln_emb_w    = (const float*)d_in[4];
    const float* ln_emb_b    = (const float*)d_in[5];
    const float* ln_col_w    = (const float*)d_in[6];
    const float* ln_col_b    = (const float*)d_in[7];
    const float* ln_prompt_w = (const float*)d_in[8];
    const float* ln_prompt_b = (const float*)d_in[9];
    const float* W_imp       = (const float*)d_in[10];
    const float* b_imp       = (const float*)d_in[11];
    const float* emb_column  = (const float*)d_in[12];
    const float* emb_prompt  = (const float*)d_in[13];
    const float* wexp        = (const float*)d_in[14];
    const float* bexp        = (const float*)d_in[15];
    float* out = (float*)d_out;

    char* ws = (char*)d_ws;
    float* colT = (float*)ws;                 // 192*100*4 = 76800 B
    float* cp   = (float*)(ws + 76800);       // 128*192*4 = 98304 B  (total 175 KB)

    precompute<<<C_SZ + P_SZ, 192, 0, stream>>>(emb_column, emb_prompt,
        ln_col_w, ln_col_b, ln_prompt_w, ln_prompt_b, W_imp, b_imp, colT, cp);
    fused<<<B_SZ, 256, 0, stream>>>(x, wfe, bfe, ln_emb_w, ln_emb_b,
        prev, W_imp, wexp, bexp, colT, cp, out);
}